// Round 18
// baseline (467.070 us; speedup 1.0000x reference)
//
#include <hip/hip_runtime.h>
#include <hip/hip_bf16.h>
#include <hip/hip_cooperative_groups.h>
#include <stdint.h>

namespace cg = cooperative_groups;

// Problem constants
#define NND   100000      // nodes
#define NED   400000      // edges
#define KD    512         // DIN
#define ND    512         // DOUT
#define PDROP 0.1f
#define INV_KEEP (1.0f/0.9f)

#define BM   64           // rows per block (A read exactly once: BN = 512 full width)
#define BKF  32           // K per step
#define NT   16           // 512/32 K-steps
#define NBLK 1564         // 100096/64

#define CSRB 391          // coop grid blocks
#define GT   (CSRB * 256) // coop total threads = 100096

typedef __attribute__((ext_vector_type(4))) float f32x4;
typedef __attribute__((ext_vector_type(8))) short short8;
typedef __attribute__((ext_vector_type(8))) unsigned short ushort8;

// ---- ws layout (bytes) ----
#define WT_OFF   102498304    // wts bf16, chunk-permuted W^T, 512 KB
#define HP_OFF   103022592    // hp_bf16 [MPAD][512]
#define DEG_OFF  205520896    // deg_u32 [NND]
#define DINV_OFF 205920896    // dinv_f32[NND]
#define OFFS_OFF 206320896    // offs_u32[NND] (CSR cursor -> local ends)
#define SRCS_OFF 206720896    // srcs_i32[NED]
#define BSUM_OFF 208320896    // block sums (391 u32)

#define SBAR()   __builtin_amdgcn_sched_barrier(0)
#define WAITV(N) asm volatile("s_waitcnt vmcnt(" #N ")" ::: "memory")
#define WAITL()  asm volatile("s_waitcnt lgkmcnt(0)" ::: "memory")

__device__ __forceinline__ unsigned short f2bf(float f) {
  unsigned int x = __float_as_uint(f);
  unsigned int r = (x + 0x7fffu + ((x >> 16) & 1u)) >> 16;
  return (unsigned short)r;
}
__device__ __forceinline__ float bf2f(unsigned short u) {
  return __uint_as_float(((unsigned int)u) << 16);
}
__device__ __forceinline__ void gload_lds16(const void* g, void* l) {
  __builtin_amdgcn_global_load_lds(
      (const __attribute__((address_space(1))) unsigned int*)g,
      (__attribute__((address_space(3))) unsigned int*)l,
      16, 0, 0);
}
// conflict-free chunk index for 16B chunk (row, g)
__device__ __forceinline__ int cfc(int row, int g) {
  return row * 4 + ((g + ((row >> 1) & 3)) & 3);
}

// ---------- ONE cooperative kernel: W-permute + deg + scan + dinv + CSR fill ----------
// Replaces memset + k_prep + k_scan1 + k_scan2 + k_fill (5 dispatches -> 1).
// 391 blocks x 256 thr (well under co-residency limit), 4 grid syncs.
__global__ void k_csr(const float* __restrict__ W, unsigned short* __restrict__ wts,
                      const int* __restrict__ ei, unsigned int* __restrict__ deg,
                      unsigned int* __restrict__ offs, unsigned int* __restrict__ bsum,
                      float* __restrict__ dinv, int* __restrict__ srcs) {
  cg::grid_group grid = cg::this_grid();
  const int t = threadIdx.x;
  const int gtid = blockIdx.x * 256 + t;

  // ---- phase 0: W chunk-permute to bf16  +  deg zero (independent) ----
  // wts[idx]: idx = kt*16384 + c*8 + e ; chunk c holds (row=c>>2, g=((c&3)-((row>>1)&3))&3)
  // value = W[kt*32 + g*8 + e][row]
  for (int idx = gtid; idx < 262144; idx += GT) {
    int kt = idx >> 14;
    int c  = (idx >> 3) & 2047;
    int e  = idx & 7;
    int row = c >> 2;
    int g = ((c & 3) - ((row >> 1) & 3)) & 3;
    int k = kt * 32 + g * 8 + e;
    wts[idx] = f2bf(W[(size_t)k * 512 + row]);
  }
  if (gtid < NND) deg[gtid] = 0u;
  grid.sync();

  // ---- phase 1: degree count (col = destination) ----
  for (int e = gtid; e < NED; e += GT) atomicAdd(&deg[ei[NED + e]], 1u);
  grid.sync();

  // ---- phase 2: per-block exclusive scan of deg -> offs (+ dinv) ----
  {
    __shared__ unsigned int s[256];
    int i = gtid;
    unsigned int v = (i < NND) ? deg[i] : 0u;
    if (i < NND) dinv[i] = rsqrtf((float)(v + 1u));   // +1 self-loop
    s[t] = v;
    __syncthreads();
    for (int d = 1; d < 256; d <<= 1) {
      unsigned int u = (t >= d) ? s[t - d] : 0u;
      __syncthreads();
      s[t] += u;
      __syncthreads();
    }
    if (i < NND) offs[i] = s[t] - v;            // block-local exclusive
    if (t == 255) bsum[blockIdx.x] = s[255];
  }
  grid.sync();

  // ---- phase 3: scan of 391 block sums (block 0 only; 512-wide ping-pong HS) ----
  if (blockIdx.x == 0) {
    __shared__ unsigned int s0[512], s1[512];
    unsigned int v0 = (t < CSRB) ? bsum[t] : 0u;
    unsigned int v1 = (t + 256 < CSRB) ? bsum[t + 256] : 0u;
    s0[t] = v0;  s0[t + 256] = v1;
    unsigned int* src = s0;
    unsigned int* dst = s1;
    __syncthreads();
    for (int d = 1; d < 512; d <<= 1) {
      for (int k = t; k < 512; k += 256)
        dst[k] = src[k] + ((k >= d) ? src[k - d] : 0u);
      __syncthreads();
      unsigned int* tmp = src; src = dst; dst = tmp;
    }
    // src = inclusive scan; exclusive = inclusive - orig
    if (t < CSRB) bsum[t] = src[t] - v0;
    if (t + 256 < CSRB) bsum[t + 256] = src[t + 256] - v1;
  }
  grid.sync();

  // ---- phase 4: CSR fill (global pos = local cursor + bsum[dst block]) ----
  for (int e = gtid; e < NED; e += GT) {
    int dst = ei[NED + e];
    unsigned int pos = atomicAdd(&offs[dst], 1u) + bsum[dst >> 8];
    srcs[pos] = ei[e];
  }
}

// ---------- fused dropout + bf16 MFMA GEMM: hp = dinv_row * (dropout(x) @ W) ----------
// R7 two-barrier schedule + two-deep A-reg pipeline (R14 exact; best measured 174 us).
// FIFO issue order: B(0) A(1) B(1) A(2) | iter j: B(j+2), A(j+3).
// ds_write A(k) auto-retires through A(k); bottom wait retires B(kt+1):
//   kt<=NT-4 -> WAITV(8); kt==NT-3 -> WAITV(6); else WAITV(0).
__global__ void __launch_bounds__(512, 4)
k_fused(const float* __restrict__ x, const float* __restrict__ dm,
        const unsigned short* __restrict__ wts,
        const float* __restrict__ dinv,
        unsigned short* __restrict__ hp) {
  __shared__ unsigned short As[2 * 2048];    // 2 x 4 KB, chunked
  __shared__ unsigned short Bs[2 * 16384];   // 2 x 32 KB, chunked

  const int t = threadIdx.x, wave = t >> 6, lane = t & 63;
  const int wm = wave >> 2, wn = wave & 3;
  const int mb = blockIdx.x * BM;

  // A staging: thread t -> row t>>3 (0..63), 4 f32 at col (t&7)*4
  const int ar = t >> 3, ag = (t & 7) >> 1, ah = t & 1;
  const bool arow_ok = (mb + ar) < NND;
  const float* xp = x + (size_t)(arow_ok ? mb + ar : 0) * KD + (t & 7) * 4;
  const float* mp = dm + (size_t)(arow_ok ? mb + ar : 0) * KD + (t & 7) * 4;
  const int awoff = cfc(ar, ag) * 16 + ah * 8;   // byte offset within an As half

  const int fr = lane & 15, kg = lane >> 4;
  const int aoff0 = cfc(wm * 32 + fr, kg) * 16;
  const int aoff1 = cfc(wm * 32 + 16 + fr, kg) * 16;

  f32x4 zero = {0.f, 0.f, 0.f, 0.f};
  f32x4 acc[2][8];
  #pragma unroll
  for (int n = 0; n < 8; ++n) { acc[0][n] = zero; acc[1][n] = zero; }

  float4 xv0, mv0, xvA, mvA, xvB, mvB;

  // ---- prologue ----
  xv0 = *(const float4*)xp;  mv0 = *(const float4*)mp;      // Aregs(0)
  {  // B(0) -> Bs[0]
    #pragma unroll
    for (int i = 0; i < 4; ++i)
      gload_lds16(wts + (size_t)(i * 512 + t) * 8, (char*)Bs + (i * 512 + t) * 16);
  }
  {  // consume Aregs(0) -> As[0]  (auto vmcnt retires xv0/mv0 only)
    ushort4 u;
    const float* xs = (const float*)&xv0; const float* ms = (const float*)&mv0;
    #pragma unroll
    for (int j = 0; j < 4; ++j)
      u[j] = (arow_ok && ms[j] >= PDROP) ? f2bf(xs[j] * INV_KEEP) : 0;
    *(ushort4*)((char*)As + awoff) = u;
  }
  xvA = *(const float4*)(xp + BKF);  mvA = *(const float4*)(mp + BKF);  // Aregs(1)
  {  // B(1) -> Bs[1]
    #pragma unroll
    for (int i = 0; i < 4; ++i)
      gload_lds16(wts + (size_t)16384 + (size_t)(i * 512 + t) * 8,
                  (char*)Bs + 32768 + (i * 512 + t) * 16);
  }
  xvB = *(const float4*)(xp + 2 * BKF);  mvB = *(const float4*)(mp + 2 * BKF);  // Aregs(2)
  SBAR(); WAITV(8); WAITL(); SBAR();    // retire B(0); As[0] visible after barrier
  __builtin_amdgcn_s_barrier();
  SBAR();

  // ---- main loop ----
  for (int kt = 0; kt < NT; ++kt) {
    const int cur = kt & 1;
    const char* ab = (const char*)As + cur * 4096;
    const char* bb = (const char*)Bs + cur * 32768;

    // compute phase: ds_read + MFMA (compiler interleaves, auto lgkm waits)
    short8 a0 = *(const short8*)(ab + aoff0);
    short8 a1 = *(const short8*)(ab + aoff1);
    #pragma unroll
    for (int n = 0; n < 8; ++n) {
      short8 b = *(const short8*)(bb + cfc(wn * 128 + n * 16 + fr, kg) * 16);
      acc[0][n] = __builtin_amdgcn_mfma_f32_16x16x32_bf16(a0, b, acc[0][n], 0, 0, 0);
      acc[1][n] = __builtin_amdgcn_mfma_f32_16x16x32_bf16(a1, b, acc[1][n], 0, 0, 0);
    }
    SBAR();
    __builtin_amdgcn_s_barrier();        // barrier 1: all waves done reading buf[cur]
    SBAR();

    // stage phase: B(kt+2) -> Bs[cur]; ds_write A(kt+1) -> As[cur^1]
    if (kt < NT - 2) {                   // B(kt+2)
      const unsigned short* src = wts + (size_t)(kt + 2) * 16384;
      char* dst = (char*)Bs + cur * 32768;
      #pragma unroll
      for (int i = 0; i < 4; ++i)
        gload_lds16(src + (size_t)(i * 512 + t) * 8, dst + (i * 512 + t) * 16);
    }
    if (kt < NT - 1) {                   // ds_write A(kt+1) from xvA (= Aregs(kt+1))
      ushort4 u;
      const float* xs = (const float*)&xvA; const float* ms = (const float*)&mvA;
      #pragma unroll
      for (int j = 0; j < 4; ++j)
        u[j] = (arow_ok && ms[j] >= PDROP) ? f2bf(xs[j] * INV_KEEP) : 0;
      *(ushort4*)((char*)As + (cur ^ 1) * 4096 + awoff) = u;
      xvA = xvB; mvA = mvB;              // shift: xvA now Aregs(kt+2)
      if (kt + 3 < NT) {                 // load Aregs(kt+3)
        xvB = *(const float4*)(xp + (kt + 3) * BKF);
        mvB = *(const float4*)(mp + (kt + 3) * BKF);
      }
    }
    SBAR();
    if (kt <= NT - 4)      { WAITV(8); } // retire B(kt+1); keep A(kt+2),B(kt+2),A(kt+3)
    else if (kt == NT - 3) { WAITV(6); } // no A(NT) load -> only 6 newer remain
    else                   { WAITV(0); }
    WAITL();                             // ds_write visible before barrier
    SBAR();
    __builtin_amdgcn_s_barrier();        // barrier 2: buf[cur^1] fully staged
    SBAR();
  }

  // epilogue: C/D layout col=lane&15, row=(lane>>4)*4+j; scale by dinv[row]
  int c0 = wn * 128 + fr;
  #pragma unroll
  for (int m = 0; m < 2; ++m) {
    int grb = mb + wm * 32 + m * 16 + kg * 4;
    #pragma unroll
    for (int j = 0; j < 4; ++j) {
      int gr = grb + j;
      if (gr < NND) {
        float dv = dinv[gr];
        size_t ro = (size_t)gr * ND + c0;
        #pragma unroll
        for (int n = 0; n < 8; ++n)
          hp[ro + n * 16] = f2bf(acc[m][n][j] * dv);
      }
    }
  }
}

// ---------- gather-aggregate: one wave per node (grid-stride), 4-edge MLP ----------
#define AGG_BLOCKS 4096
__global__ void k_aggregate(const unsigned int* __restrict__ lends,   // local ends
                            const unsigned int* __restrict__ bsum,
                            const unsigned int* __restrict__ deg,
                            const int* __restrict__ srcs,
                            const unsigned short* __restrict__ hp,
                            const float* __restrict__ dinv,
                            const float* __restrict__ b,
                            float* __restrict__ out) {
  int lane = threadIdx.x & 63;
  int q = lane * 8;
  const unsigned short* hq = hp + q;
  f32x4 b0 = *(const f32x4*)(b + q);
  f32x4 b1 = *(const f32x4*)(b + q + 4);

  for (int node = blockIdx.x * 4 + (threadIdx.x >> 6); node < NND;
       node += AGG_BLOCKS * 4) {
    float acc[8];
    ushort8 hs = *(const ushort8*)(hq + (size_t)node * ND);   // self-loop
    #pragma unroll
    for (int j = 0; j < 8; ++j) acc[j] = bf2f(hs[j]);

    unsigned int d = deg[node];
    unsigned int end = lends[node] + bsum[node >> 8];
    unsigned int e = end - d;
    // 4 independent 1-KB gathers in flight per iteration
    for (; e + 4 <= end; e += 4) {
      int s0 = srcs[e + 0], s1 = srcs[e + 1], s2 = srcs[e + 2], s3 = srcs[e + 3];
      ushort8 h0 = *(const ushort8*)(hq + (size_t)s0 * ND);
      ushort8 h1 = *(const ushort8*)(hq + (size_t)s1 * ND);
      ushort8 h2 = *(const ushort8*)(hq + (size_t)s2 * ND);
      ushort8 h3 = *(const ushort8*)(hq + (size_t)s3 * ND);
      #pragma unroll
      for (int j = 0; j < 8; ++j)
        acc[j] += (bf2f(h0[j]) + bf2f(h1[j])) + (bf2f(h2[j]) + bf2f(h3[j]));
    }
    for (; e < end; ++e) {
      int s = srcs[e];
      ushort8 hv = *(const ushort8*)(hq + (size_t)s * ND);
      #pragma unroll
      for (int j = 0; j < 8; ++j) acc[j] += bf2f(hv[j]);
    }

    float dv = dinv[node];
    f32x4 o0, o1;
    o0[0] = acc[0] * dv + b0[0]; o0[1] = acc[1] * dv + b0[1];
    o0[2] = acc[2] * dv + b0[2]; o0[3] = acc[3] * dv + b0[3];
    o1[0] = acc[4] * dv + b1[0]; o1[1] = acc[5] * dv + b1[1];
    o1[2] = acc[6] * dv + b1[2]; o1[3] = acc[7] * dv + b1[3];
    float* op = out + (size_t)node * ND + q;
    __builtin_nontemporal_store(o0, (f32x4*)op);
    __builtin_nontemporal_store(o1, (f32x4*)(op + 4));
  }
}

extern "C" void kernel_launch(void* const* d_in, const int* in_sizes, int n_in,
                              void* d_out, int out_size, void* d_ws, size_t ws_size,
                              hipStream_t stream) {
  const float* x  = (const float*)d_in[0];
  const int*   ei = (const int*)d_in[1];     // int64 in reference -> int32 in harness
  const float* W  = (const float*)d_in[2];
  const float* b  = (const float*)d_in[3];
  const float* dm = (const float*)d_in[4];
  float* out = (float*)d_out;

  char* ws = (char*)d_ws;
  unsigned short* wts  = (unsigned short*)(ws + WT_OFF);
  unsigned short* hp   = (unsigned short*)(ws + HP_OFF);
  unsigned int*   deg  = (unsigned int*)(ws + DEG_OFF);
  float*          dinv = (float*)(ws + DINV_OFF);
  unsigned int*   offs = (unsigned int*)(ws + OFFS_OFF);
  int*            srcs = (int*)(ws + SRCS_OFF);
  unsigned int*   bsum = (unsigned int*)(ws + BSUM_OFF);

  void* csr_args[] = {(void*)&W, (void*)&wts, (void*)&ei, (void*)&deg,
                      (void*)&offs, (void*)&bsum, (void*)&dinv, (void*)&srcs};
  hipLaunchCooperativeKernel((void*)k_csr, dim3(CSRB), dim3(256), csr_args, 0, stream);
  hipLaunchKernelGGL(k_fused,     dim3(NBLK),       dim3(512), 0, stream, x, dm, wts, dinv, hp);
  hipLaunchKernelGGL(k_aggregate, dim3(AGG_BLOCKS), dim3(256), 0, stream, offs, bsum, deg, srcs, hp, dinv, b, out);
}

// Round 19
// 292.234 us; speedup vs baseline: 1.5983x; 1.5983x over previous
//
#include <hip/hip_runtime.h>
#include <hip/hip_bf16.h>
#include <stdint.h>

// Problem constants
#define NND   100000      // nodes
#define NED   400000      // edges
#define KD    512         // DIN
#define ND    512         // DOUT
#define PDROP 0.1f
#define INV_KEEP (1.0f/0.9f)

#define BM   64           // rows per block (A read exactly once: BN = 512 full width)
#define BKF  32           // K per step
#define NT   16           // 512/32 K-steps
#define NBLK 1564         // 100096/64

typedef __attribute__((ext_vector_type(4))) float f32x4;
typedef __attribute__((ext_vector_type(8))) short short8;
typedef __attribute__((ext_vector_type(8))) unsigned short ushort8;

// ---- ws layout (bytes) ----
#define WT_OFF   102498304    // wts bf16, chunk-permuted W^T, 512 KB
#define HP_OFF   103022592    // hp_bf16 [MPAD][512]
#define DEG_OFF  205520896    // deg_u32 [NND]
#define DINV_OFF 205920896    // dinv_f32[NND]
#define OFFS_OFF 206320896    // offs_u32[NND] (CSR cursor -> local ends)
#define SRCS_OFF 206720896    // srcs_i32[NED]
#define BSUM_OFF 208320896    // block sums (391 u32)

#define SBAR()   __builtin_amdgcn_sched_barrier(0)
#define WAITV(N) asm volatile("s_waitcnt vmcnt(" #N ")" ::: "memory")
#define WAITL()  asm volatile("s_waitcnt lgkmcnt(0)" ::: "memory")

__device__ __forceinline__ unsigned short f2bf(float f) {
  unsigned int x = __float_as_uint(f);
  unsigned int r = (x + 0x7fffu + ((x >> 16) & 1u)) >> 16;
  return (unsigned short)r;
}
__device__ __forceinline__ float bf2f(unsigned short u) {
  return __uint_as_float(((unsigned int)u) << 16);
}
__device__ __forceinline__ void gload_lds16(const void* g, void* l) {
  __builtin_amdgcn_global_load_lds(
      (const __attribute__((address_space(1))) unsigned int*)g,
      (__attribute__((address_space(3))) unsigned int*)l,
      16, 0, 0);
}
// conflict-free chunk index for 16B chunk (row, g)
__device__ __forceinline__ int cfc(int row, int g) {
  return row * 4 + ((g + ((row >> 1) & 3)) & 3);
}

// ---------- prep: chunk-permuted W^T to bf16 (blocks 0..1023) + degree count ----------
// Same bijection as before, COALESCED-READ form: thread idx reads W[idx] (4B
// consecutive), computes scattered write index.  (k,row) -> widx:
//   kt=k>>5, g=(k>>3)&3, e=k&7, c=row*4+((g+((row>>1)&3))&3), widx=kt*16384+c*8+e
// so wts[widx] holds W[k][row] = W^T[row][k], chunk c = (row, g) as k_fused expects.
__global__ void k_prep(const float* __restrict__ W, unsigned short* __restrict__ wts,
                       const int* __restrict__ ei, unsigned int* __restrict__ deg) {
  int bb = blockIdx.x;
  if (bb < 1024) {
    int idx = bb * 256 + threadIdx.x;        // 262144 total, coalesced W read
    int k = idx >> 9, row = idx & 511;
    int kt = k >> 5;
    int g  = (k >> 3) & 3;
    int e  = k & 7;
    int c  = row * 4 + ((g + ((row >> 1) & 3)) & 3);
    wts[kt * 16384 + c * 8 + e] = f2bf(W[idx]);
  } else {
    int e = (bb - 1024) * 256 + threadIdx.x;
    if (e < NED) atomicAdd(&deg[ei[NED + e]], 1u);   // col = destination
  }
}

// ---------- exclusive scan of deg -> offs (+ dinv fused) ----------
__global__ void k_scan1(const unsigned int* __restrict__ deg,
                        unsigned int* __restrict__ offs, unsigned int* __restrict__ bsum,
                        float* __restrict__ dinv) {
  __shared__ unsigned int s[256];
  int tid = threadIdx.x;
  int i = blockIdx.x * 256 + tid;
  unsigned int v = (i < NND) ? deg[i] : 0u;
  if (i < NND) dinv[i] = rsqrtf((float)(v + 1u));   // +1 self-loop
  s[tid] = v;
  __syncthreads();
  for (int d = 1; d < 256; d <<= 1) {
    unsigned int t = (tid >= d) ? s[tid - d] : 0u;
    __syncthreads();
    s[tid] += t;
    __syncthreads();
  }
  if (i < NND) offs[i] = s[tid] - v;          // block-local exclusive
  if (tid == 255) bsum[blockIdx.x] = s[255];
}
__global__ void k_scan2(unsigned int* __restrict__ bsum) {   // 391 entries
  __shared__ unsigned int s[512];
  int t = threadIdx.x;
  unsigned int v = (t < 391) ? bsum[t] : 0u;
  s[t] = v;
  __syncthreads();
  for (int d = 1; d < 512; d <<= 1) {
    unsigned int u = (t >= d) ? s[t - d] : 0u;
    __syncthreads();
    s[t] += u;
    __syncthreads();
  }
  if (t < 391) bsum[t] = s[t] - v;            // exclusive block offsets
}

// ---------- CSR fill (global pos = local cursor + bsum[dst block]) ----------
__global__ void k_fill(const int* __restrict__ ei, unsigned int* __restrict__ offs,
                       const unsigned int* __restrict__ bsum, int* __restrict__ srcs) {
  int e = blockIdx.x * 256 + threadIdx.x;
  if (e < NED) {
    int dst = ei[NED + e];
    unsigned int pos = atomicAdd(&offs[dst], 1u) + bsum[dst >> 8];
    srcs[pos] = ei[e];
  }
}

// ---------- fused dropout + bf16 MFMA GEMM: hp = dinv_row * (dropout(x) @ W) ----------
// R7 two-barrier schedule + two-deep A-reg pipeline (R14 exact; best measured 174 us).
// FIFO issue order: B(0) A(1) B(1) A(2) | iter j: B(j+2), A(j+3).
// ds_write A(k) auto-retires through A(k); bottom wait retires B(kt+1):
//   kt<=NT-4 -> WAITV(8); kt==NT-3 -> WAITV(6); else WAITV(0).
__global__ void __launch_bounds__(512, 4)
k_fused(const float* __restrict__ x, const float* __restrict__ dm,
        const unsigned short* __restrict__ wts,
        const float* __restrict__ dinv,
        unsigned short* __restrict__ hp) {
  __shared__ unsigned short As[2 * 2048];    // 2 x 4 KB, chunked
  __shared__ unsigned short Bs[2 * 16384];   // 2 x 32 KB, chunked

  const int t = threadIdx.x, wave = t >> 6, lane = t & 63;
  const int wm = wave >> 2, wn = wave & 3;
  const int mb = blockIdx.x * BM;

  // A staging: thread t -> row t>>3 (0..63), 4 f32 at col (t&7)*4
  const int ar = t >> 3, ag = (t & 7) >> 1, ah = t & 1;
  const bool arow_ok = (mb + ar) < NND;
  const float* xp = x + (size_t)(arow_ok ? mb + ar : 0) * KD + (t & 7) * 4;
  const float* mp = dm + (size_t)(arow_ok ? mb + ar : 0) * KD + (t & 7) * 4;
  const int awoff = cfc(ar, ag) * 16 + ah * 8;   // byte offset within an As half

  const int fr = lane & 15, kg = lane >> 4;
  const int aoff0 = cfc(wm * 32 + fr, kg) * 16;
  const int aoff1 = cfc(wm * 32 + 16 + fr, kg) * 16;

  f32x4 zero = {0.f, 0.f, 0.f, 0.f};
  f32x4 acc[2][8];
  #pragma unroll
  for (int n = 0; n < 8; ++n) { acc[0][n] = zero; acc[1][n] = zero; }

  float4 xv0, mv0, xvA, mvA, xvB, mvB;

  // ---- prologue ----
  xv0 = *(const float4*)xp;  mv0 = *(const float4*)mp;      // Aregs(0)
  {  // B(0) -> Bs[0]
    #pragma unroll
    for (int i = 0; i < 4; ++i)
      gload_lds16(wts + (size_t)(i * 512 + t) * 8, (char*)Bs + (i * 512 + t) * 16);
  }
  {  // consume Aregs(0) -> As[0]  (auto vmcnt retires xv0/mv0 only)
    ushort4 u;
    const float* xs = (const float*)&xv0; const float* ms = (const float*)&mv0;
    #pragma unroll
    for (int j = 0; j < 4; ++j)
      u[j] = (arow_ok && ms[j] >= PDROP) ? f2bf(xs[j] * INV_KEEP) : 0;
    *(ushort4*)((char*)As + awoff) = u;
  }
  xvA = *(const float4*)(xp + BKF);  mvA = *(const float4*)(mp + BKF);  // Aregs(1)
  {  // B(1) -> Bs[1]
    #pragma unroll
    for (int i = 0; i < 4; ++i)
      gload_lds16(wts + (size_t)16384 + (size_t)(i * 512 + t) * 8,
                  (char*)Bs + 32768 + (i * 512 + t) * 16);
  }
  xvB = *(const float4*)(xp + 2 * BKF);  mvB = *(const float4*)(mp + 2 * BKF);  // Aregs(2)
  SBAR(); WAITV(8); WAITL(); SBAR();    // retire B(0); As[0] visible after barrier
  __builtin_amdgcn_s_barrier();
  SBAR();

  // ---- main loop ----
  for (int kt = 0; kt < NT; ++kt) {
    const int cur = kt & 1;
    const char* ab = (const char*)As + cur * 4096;
    const char* bb = (const char*)Bs + cur * 32768;

    // compute phase: ds_read + MFMA (compiler interleaves, auto lgkm waits)
    short8 a0 = *(const short8*)(ab + aoff0);
    short8 a1 = *(const short8*)(ab + aoff1);
    #pragma unroll
    for (int n = 0; n < 8; ++n) {
      short8 b = *(const short8*)(bb + cfc(wn * 128 + n * 16 + fr, kg) * 16);
      acc[0][n] = __builtin_amdgcn_mfma_f32_16x16x32_bf16(a0, b, acc[0][n], 0, 0, 0);
      acc[1][n] = __builtin_amdgcn_mfma_f32_16x16x32_bf16(a1, b, acc[1][n], 0, 0, 0);
    }
    SBAR();
    __builtin_amdgcn_s_barrier();        // barrier 1: all waves done reading buf[cur]
    SBAR();

    // stage phase: B(kt+2) -> Bs[cur]; ds_write A(kt+1) -> As[cur^1]
    if (kt < NT - 2) {                   // B(kt+2)
      const unsigned short* src = wts + (size_t)(kt + 2) * 16384;
      char* dst = (char*)Bs + cur * 32768;
      #pragma unroll
      for (int i = 0; i < 4; ++i)
        gload_lds16(src + (size_t)(i * 512 + t) * 8, dst + (i * 512 + t) * 16);
    }
    if (kt < NT - 1) {                   // ds_write A(kt+1) from xvA (= Aregs(kt+1))
      ushort4 u;
      const float* xs = (const float*)&xvA; const float* ms = (const float*)&mvA;
      #pragma unroll
      for (int j = 0; j < 4; ++j)
        u[j] = (arow_ok && ms[j] >= PDROP) ? f2bf(xs[j] * INV_KEEP) : 0;
      *(ushort4*)((char*)As + (cur ^ 1) * 4096 + awoff) = u;
      xvA = xvB; mvA = mvB;              // shift: xvA now Aregs(kt+2)
      if (kt + 3 < NT) {                 // load Aregs(kt+3)
        xvB = *(const float4*)(xp + (kt + 3) * BKF);
        mvB = *(const float4*)(mp + (kt + 3) * BKF);
      }
    }
    SBAR();
    if (kt <= NT - 4)      { WAITV(8); } // retire B(kt+1); keep A(kt+2),B(kt+2),A(kt+3)
    else if (kt == NT - 3) { WAITV(6); } // no A(NT) load -> only 6 newer remain
    else                   { WAITV(0); }
    WAITL();                             // ds_write visible before barrier
    SBAR();
    __builtin_amdgcn_s_barrier();        // barrier 2: buf[cur^1] fully staged
    SBAR();
  }

  // epilogue: C/D layout col=lane&15, row=(lane>>4)*4+j; scale by dinv[row]
  int c0 = wn * 128 + fr;
  #pragma unroll
  for (int m = 0; m < 2; ++m) {
    int grb = mb + wm * 32 + m * 16 + kg * 4;
    #pragma unroll
    for (int j = 0; j < 4; ++j) {
      int gr = grb + j;
      if (gr < NND) {
        float dv = dinv[gr];
        size_t ro = (size_t)gr * ND + c0;
        #pragma unroll
        for (int n = 0; n < 8; ++n)
          hp[ro + n * 16] = f2bf(acc[m][n][j] * dv);
      }
    }
  }
}

// ---------- gather-aggregate: one wave per node, 4-edge memory-level parallelism ----------
__global__ void k_aggregate(const unsigned int* __restrict__ lends,   // local ends
                            const unsigned int* __restrict__ bsum,
                            const unsigned int* __restrict__ deg,
                            const int* __restrict__ srcs,
                            const unsigned short* __restrict__ hp,
                            const float* __restrict__ dinv,
                            const float* __restrict__ b,
                            float* __restrict__ out) {
  int node = blockIdx.x * 4 + (threadIdx.x >> 6);
  if (node >= NND) return;
  int lane = threadIdx.x & 63;
  int q = lane * 8;
  const unsigned short* hq = hp + q;

  float acc[8];
  ushort8 hs = *(const ushort8*)(hq + (size_t)node * ND);   // self-loop
  #pragma unroll
  for (int j = 0; j < 8; ++j) acc[j] = bf2f(hs[j]);

  unsigned int d = deg[node];
  unsigned int end = lends[node] + bsum[node >> 8];
  unsigned int e = end - d;
  // 4 independent 1-KB gathers in flight per iteration
  for (; e + 4 <= end; e += 4) {
    int s0 = srcs[e + 0], s1 = srcs[e + 1], s2 = srcs[e + 2], s3 = srcs[e + 3];
    ushort8 h0 = *(const ushort8*)(hq + (size_t)s0 * ND);
    ushort8 h1 = *(const ushort8*)(hq + (size_t)s1 * ND);
    ushort8 h2 = *(const ushort8*)(hq + (size_t)s2 * ND);
    ushort8 h3 = *(const ushort8*)(hq + (size_t)s3 * ND);
    #pragma unroll
    for (int j = 0; j < 8; ++j)
      acc[j] += (bf2f(h0[j]) + bf2f(h1[j])) + (bf2f(h2[j]) + bf2f(h3[j]));
  }
  for (; e < end; ++e) {
    int s = srcs[e];
    ushort8 hv = *(const ushort8*)(hq + (size_t)s * ND);
    #pragma unroll
    for (int j = 0; j < 8; ++j) acc[j] += bf2f(hv[j]);
  }

  float dv = dinv[node];
  float4 b0 = *(const float4*)(b + q);
  float4 b1 = *(const float4*)(b + q + 4);
  float4 o0, o1;
  o0.x = acc[0] * dv + b0.x; o0.y = acc[1] * dv + b0.y;
  o0.z = acc[2] * dv + b0.z; o0.w = acc[3] * dv + b0.w;
  o1.x = acc[4] * dv + b1.x; o1.y = acc[5] * dv + b1.y;
  o1.z = acc[6] * dv + b1.z; o1.w = acc[7] * dv + b1.w;
  float* op = out + (size_t)node * ND + q;
  *(float4*)op = o0;
  *(float4*)(op + 4) = o1;
}

extern "C" void kernel_launch(void* const* d_in, const int* in_sizes, int n_in,
                              void* d_out, int out_size, void* d_ws, size_t ws_size,
                              hipStream_t stream) {
  const float* x  = (const float*)d_in[0];
  const int*   ei = (const int*)d_in[1];     // int64 in reference -> int32 in harness
  const float* W  = (const float*)d_in[2];
  const float* b  = (const float*)d_in[3];
  const float* dm = (const float*)d_in[4];
  float* out = (float*)d_out;

  char* ws = (char*)d_ws;
  unsigned short* wts  = (unsigned short*)(ws + WT_OFF);
  unsigned short* hp   = (unsigned short*)(ws + HP_OFF);
  unsigned int*   deg  = (unsigned int*)(ws + DEG_OFF);
  float*          dinv = (float*)(ws + DINV_OFF);
  unsigned int*   offs = (unsigned int*)(ws + OFFS_OFF);
  int*            srcs = (int*)(ws + SRCS_OFF);
  unsigned int*   bsum = (unsigned int*)(ws + BSUM_OFF);

  hipMemsetAsync(deg, 0, NND * sizeof(unsigned int), stream);
  hipLaunchKernelGGL(k_prep,      dim3(2587),  dim3(256), 0, stream, W, wts, ei, deg);
  hipLaunchKernelGGL(k_scan1,     dim3(391),   dim3(256), 0, stream, deg, offs, bsum, dinv);
  hipLaunchKernelGGL(k_scan2,     dim3(1),     dim3(512), 0, stream, bsum);
  hipLaunchKernelGGL(k_fill,      dim3(1563),  dim3(256), 0, stream, ei, offs, bsum, srcs);
  hipLaunchKernelGGL(k_fused,     dim3(NBLK),  dim3(512), 0, stream, x, dm, wts, dinv, hp);
  hipLaunchKernelGGL(k_aggregate, dim3(25000), dim3(256), 0, stream, offs, bsum, deg, srcs, hp, dinv, b, out);
}